// Round 11
// baseline (740.919 us; speedup 1.0000x reference)
//
#include <hip/hip_runtime.h>
#include <hip/hip_fp16.h>
#include <math.h>

#define FIN 64
#define HID 64
#define FOUT 40
#define LDSU 36         // uint stride per staged LDS row (144 B): pad breaks conflicts
#define CCHUNK 4096     // edges per partition block
#define BNODES 64       // nodes per bucket
#define ASTRIDE 65      // fp32 stride per local-node accumulator row (odd -> bank spread)
#define MAXBUCK 1600    // LDS capacity for bucket cursors/hists (>= nbuck)

typedef __attribute__((ext_vector_type(8))) short short8;
typedef __attribute__((ext_vector_type(4))) float f32x4;

__device__ __forceinline__ __half2 u2h(unsigned u) { return *(__half2*)&u; }
__device__ __forceinline__ unsigned h2u(__half2 h) { return *(unsigned*)&h; }

// ================= CSR-lite build: bucket counting sort (no global atomics) ==========
// bucket = dst >> 6 (64 nodes per bucket). Pack: src (20 bits) | local_dst << 20.

__global__ __launch_bounds__(256) void bucket_hist_kernel(const int* __restrict__ dst,
        int* __restrict__ cnt, int E, int nbuck, int nblkc) {
    __shared__ int hist[MAXBUCK];
    int tid = threadIdx.x;
    for (int i = tid; i < nbuck; i += 256) hist[i] = 0;
    __syncthreads();
    int base = blockIdx.x * CCHUNK;
    int lim = min(CCHUNK, E - base);
    for (int i = tid; i < lim; i += 256)
        atomicAdd(&hist[dst[base + i] >> 6], 1);
    __syncthreads();
    for (int b = tid; b < nbuck; b += 256)
        cnt[b * nblkc + blockIdx.x] = hist[b];
}

// Per-bucket exclusive scan over the nblkc block counts; total per bucket.
__global__ __launch_bounds__(256) void bucket_colscan_kernel(int* __restrict__ cnt,
        int* __restrict__ total, int nblkc) {
    int b = blockIdx.x;
    int tid = threadIdx.x, lane = tid & 63, wid = tid >> 6;
    int v = (tid < nblkc) ? cnt[b * nblkc + tid] : 0;
    int incl = v;
    #pragma unroll
    for (int off = 1; off < 64; off <<= 1) {
        int t2 = __shfl_up(incl, off);
        if (lane >= off) incl += t2;
    }
    __shared__ int ws[4];
    if (lane == 63) ws[wid] = incl;
    __syncthreads();
    int woff = 0;
    for (int w2 = 0; w2 < wid; ++w2) woff += ws[w2];
    int excl = woff + incl - v;
    if (tid < nblkc) cnt[b * nblkc + tid] = excl;
    if (tid == 255) total[b] = woff + incl;
}

// Single block: exclusive scan of nbuck (~1563) bucket totals -> bstart[0..nbuck].
__global__ __launch_bounds__(256) void bucket_scan_kernel(const int* __restrict__ total,
        int* __restrict__ bstart, int nbuck) {
    __shared__ int tsum[256];
    int tid = threadIdx.x;
    int per = (nbuck + 256) / 256 + 1;   // cover nbuck+1 entries
    int st = tid * per;
    int s = 0;
    for (int k = 0; k < per; ++k) {
        int i = st + k;
        if (i < nbuck) s += total[i];
    }
    tsum[tid] = s;
    __syncthreads();
    if (tid == 0) {
        int run = 0;
        for (int i = 0; i < 256; ++i) { int v = tsum[i]; tsum[i] = run; run += v; }
    }
    __syncthreads();
    int run = tsum[tid];
    for (int k = 0; k < per; ++k) {
        int i = st + k;
        if (i <= nbuck) {
            bstart[i] = run;
            if (i < nbuck) run += total[i];
        }
    }
}

// Partition edges into bucket-ordered ebuf (packed). LDS cursors only.
__global__ __launch_bounds__(256) void partition_kernel(const int* __restrict__ src,
        const int* __restrict__ dst, const int* __restrict__ cnt,
        const int* __restrict__ bstart, unsigned* __restrict__ ebuf,
        int E, int nbuck, int nblkc) {
    __shared__ int cur[MAXBUCK];
    int tid = threadIdx.x;
    int r = blockIdx.x;
    for (int b = tid; b < nbuck; b += 256)
        cur[b] = bstart[b] + cnt[b * nblkc + r];
    __syncthreads();
    int base = r * CCHUNK;
    int lim = min(CCHUNK, E - base);
    for (int i = tid; i < lim; i += 256) {
        int d = dst[base + i];
        int s = src[base + i];
        int b = d >> 6;
        int pos = atomicAdd(&cur[b], 1);       // LDS atomic
        ebuf[pos] = (unsigned)s | ((unsigned)(d & 63) << 20);
    }
}

// Per-bucket degree histogram -> dinv (needed before gemm1).
__global__ __launch_bounds__(256) void dinv_kernel(const unsigned* __restrict__ ebuf,
        const int* __restrict__ bstart, float* __restrict__ dinv, int n) {
    __shared__ int hist[BNODES];
    int tid = threadIdx.x, bkt = blockIdx.x;
    int base = bstart[bkt], m = bstart[bkt + 1] - base;
    if (tid < BNODES) hist[tid] = 0;
    __syncthreads();
    for (int i = tid; i < m; i += 256)
        atomicAdd(&hist[ebuf[base + i] >> 20], 1);
    __syncthreads();
    int node = bkt * BNODES + tid;
    if (tid < BNODES && node < n)
        dinv[node] = rsqrtf((float)hist[tid] + 1.0f);
}

// ================= layer 1 GEMM (MFMA f16): h1s = f16( (x @ W1) * dinv ) =================

__global__ __launch_bounds__(256) void gemm1_mfma(const float* __restrict__ x,
        const float* __restrict__ W, const float* __restrict__ dinv,
        __half* __restrict__ h, int n) {
    __shared__ unsigned As[64 * LDSU];
    int tid = threadIdx.x;
    int lane = tid & 63;
    int w = tid >> 6;
    int q = lane >> 4;        // 0..3 k-block / row-quad
    int c = lane & 15;        // col within tile
    int nodeBase = blockIdx.x * 64;

    #pragma unroll
    for (int i = 0; i < 4; ++i) {
        int fidx = tid + 256 * i;          // float4 index 0..1023
        int row = fidx >> 4, c4 = fidx & 15;
        int node = nodeBase + row; if (node >= n) node = n - 1;
        float4 v = *(const float4*)(x + (size_t)node * 64 + c4 * 4);
        As[row * LDSU + c4 * 2 + 0] = h2u(__floats2half2_rn(v.x, v.y));
        As[row * LDSU + c4 * 2 + 1] = h2u(__floats2half2_rn(v.z, v.w));
    }
    short8 Bf[4][2];
    #pragma unroll
    for (int nt = 0; nt < 4; ++nt)
        #pragma unroll
        for (int kk = 0; kk < 2; ++kk)
            #pragma unroll
            for (int j = 0; j < 8; ++j)
                Bf[nt][kk][j] = (short)__half_as_ushort(
                    __float2half(W[(kk * 32 + q * 8 + j) * 64 + nt * 16 + c]));
    __syncthreads();

    f32x4 acc[4];
    #pragma unroll
    for (int nt = 0; nt < 4; ++nt) acc[nt] = (f32x4){0.f, 0.f, 0.f, 0.f};
    #pragma unroll
    for (int kk = 0; kk < 2; ++kk) {
        short8 a = *(const short8*)&As[(w * 16 + c) * LDSU + kk * 16 + q * 4];
        #pragma unroll
        for (int nt = 0; nt < 4; ++nt)
            acc[nt] = __builtin_amdgcn_mfma_f32_16x16x32_f16(a, Bf[nt][kk], acc[nt], 0, 0, 0);
    }
    unsigned short* hu = (unsigned short*)h;
    #pragma unroll
    for (int r = 0; r < 4; ++r) {
        int node = nodeBase + w * 16 + q * 4 + r;
        if (node < n) {
            float dv = dinv[node];
            #pragma unroll
            for (int nt = 0; nt < 4; ++nt)
                hu[(size_t)node * 64 + nt * 16 + c] =
                    __half_as_ushort(__float2half(acc[nt][r] * dv));
        }
    }
}

// ================= edge-centric aggregation, layer 1 =================
// One block per 64-node bucket. Sequential ebuf reads; quarter-wave row gather
// (4 edges per load, unroll x2); fp32 LDS accumulate (ds_add_f32, stride 65).
// Epilogue: rs[d] = f16( relu( dinv*(sum + h1s[d]) + b1 ) * dinv ).

__global__ __launch_bounds__(256) void edge_agg1_kernel(const __half* __restrict__ h1s,
        const unsigned* __restrict__ ebuf, const int* __restrict__ bstart,
        const float* __restrict__ dinv, const float* __restrict__ b,
        __half* __restrict__ rs, int n) {
    __shared__ float accum[BNODES * ASTRIDE];
    int tid = threadIdx.x, bkt = blockIdx.x;
    int base = bstart[bkt];
    int m = bstart[bkt + 1] - base;
    int nodeBase = bkt * BNODES;
    for (int i = tid; i < BNODES * ASTRIDE; i += 256) accum[i] = 0.f;
    __syncthreads();
    int wid = tid >> 6, lane = tid & 63;
    int q = lane >> 4;            // quarter = which edge of the group
    int i4 = lane & 15;           // uint2 index within row (features 4*i4..4*i4+3)
    const uint2* hv = (const uint2*)h1s;
    for (int g = wid * 8; g < m; g += 32) {
        int eA = g + q, eB = g + 4 + q;
        if (eA < m) {
            unsigned p = ebuf[base + eA];
            uint2 v = hv[(size_t)(p & 0xFFFFF) * 16 + i4];
            float2 f0 = __half22float2(u2h(v.x));
            float2 f1 = __half22float2(u2h(v.y));
            float* ap = &accum[(p >> 20) * ASTRIDE + i4 * 4];
            atomicAdd(ap + 0, f0.x); atomicAdd(ap + 1, f0.y);
            atomicAdd(ap + 2, f1.x); atomicAdd(ap + 3, f1.y);
        }
        if (eB < m) {
            unsigned p = ebuf[base + eB];
            uint2 v = hv[(size_t)(p & 0xFFFFF) * 16 + i4];
            float2 f0 = __half22float2(u2h(v.x));
            float2 f1 = __half22float2(u2h(v.y));
            float* ap = &accum[(p >> 20) * ASTRIDE + i4 * 4];
            atomicAdd(ap + 0, f0.x); atomicAdd(ap + 1, f0.y);
            atomicAdd(ap + 2, f1.x); atomicAdd(ap + 3, f1.y);
        }
    }
    __syncthreads();
    const unsigned* selfu = (const unsigned*)h1s;
    unsigned* rsu = (unsigned*)rs;
    for (int idx = tid; idx < BNODES * 32; idx += 256) {
        int row = idx >> 5, pr = idx & 31;      // pr = half2 pair (features 2pr, 2pr+1)
        int node = nodeBase + row;
        if (node < n) {
            float dv = dinv[node];
            float2 sf = __half22float2(u2h(selfu[(size_t)node * 32 + pr]));
            float z0 = dv * (accum[row * ASTRIDE + 2 * pr] + sf.x) + b[2 * pr];
            float z1 = dv * (accum[row * ASTRIDE + 2 * pr + 1] + sf.y) + b[2 * pr + 1];
            float r0 = fmaxf(z0, 0.f) * dv;
            float r1 = fmaxf(z1, 0.f) * dv;
            rsu[(size_t)node * 32 + pr] = h2u(__floats2half2_rn(r0, r1));
        }
    }
}

// ================= edge-centric aggregation, layer 2 =================
// Same structure over rs. Epilogue: s[d] = f16( dinv * (sum + rs[d]) ).
// (A_hat @ (r @ W2) == (A_hat @ r) @ W2 — GEMM happens after, fused with softmax.)

__global__ __launch_bounds__(256) void edge_agg2_kernel(const __half* __restrict__ rs,
        const unsigned* __restrict__ ebuf, const int* __restrict__ bstart,
        const float* __restrict__ dinv, __half* __restrict__ sh, int n) {
    __shared__ float accum[BNODES * ASTRIDE];
    int tid = threadIdx.x, bkt = blockIdx.x;
    int base = bstart[bkt];
    int m = bstart[bkt + 1] - base;
    int nodeBase = bkt * BNODES;
    for (int i = tid; i < BNODES * ASTRIDE; i += 256) accum[i] = 0.f;
    __syncthreads();
    int wid = tid >> 6, lane = tid & 63;
    int q = lane >> 4;
    int i4 = lane & 15;
    const uint2* hv = (const uint2*)rs;
    for (int g = wid * 8; g < m; g += 32) {
        int eA = g + q, eB = g + 4 + q;
        if (eA < m) {
            unsigned p = ebuf[base + eA];
            uint2 v = hv[(size_t)(p & 0xFFFFF) * 16 + i4];
            float2 f0 = __half22float2(u2h(v.x));
            float2 f1 = __half22float2(u2h(v.y));
            float* ap = &accum[(p >> 20) * ASTRIDE + i4 * 4];
            atomicAdd(ap + 0, f0.x); atomicAdd(ap + 1, f0.y);
            atomicAdd(ap + 2, f1.x); atomicAdd(ap + 3, f1.y);
        }
        if (eB < m) {
            unsigned p = ebuf[base + eB];
            uint2 v = hv[(size_t)(p & 0xFFFFF) * 16 + i4];
            float2 f0 = __half22float2(u2h(v.x));
            float2 f1 = __half22float2(u2h(v.y));
            float* ap = &accum[(p >> 20) * ASTRIDE + i4 * 4];
            atomicAdd(ap + 0, f0.x); atomicAdd(ap + 1, f0.y);
            atomicAdd(ap + 2, f1.x); atomicAdd(ap + 3, f1.y);
        }
    }
    __syncthreads();
    const unsigned* selfu = (const unsigned*)rs;
    unsigned* shu = (unsigned*)sh;
    for (int idx = tid; idx < BNODES * 32; idx += 256) {
        int row = idx >> 5, pr = idx & 31;
        int node = nodeBase + row;
        if (node < n) {
            float dv = dinv[node];
            float2 sf = __half22float2(u2h(selfu[(size_t)node * 32 + pr]));
            float s0 = dv * (accum[row * ASTRIDE + 2 * pr] + sf.x);
            float s1 = dv * (accum[row * ASTRIDE + 2 * pr + 1] + sf.y);
            shu[(size_t)node * 32 + pr] = h2u(__floats2half2_rn(s0, s1));
        }
    }
}

// ================= layer 2 GEMM + fused log_softmax (MFMA f16) =================
// out = log_softmax( sh @ W2 + b2 ). Row reduction = shfl_xor over the 16 c-lanes.

__global__ __launch_bounds__(256) void gemm2_softmax(const __half* __restrict__ sh,
        const float* __restrict__ W, const float* __restrict__ b2,
        float* __restrict__ out, int n) {
    __shared__ unsigned As[64 * LDSU];
    int tid = threadIdx.x;
    int lane = tid & 63;
    int w = tid >> 6;
    int q = lane >> 4;
    int c = lane & 15;
    int nodeBase = blockIdx.x * 64;
    const unsigned* a1u = (const unsigned*)sh;

    #pragma unroll
    for (int i = 0; i < 8; ++i) {
        int uidx = tid + 256 * i;          // 0..2047
        int row = uidx >> 5, col = uidx & 31;
        int node = nodeBase + row; if (node >= n) node = n - 1;
        As[row * LDSU + col] = a1u[(size_t)node * 32 + col];
    }
    short8 Bf[3][2];
    #pragma unroll
    for (int nt = 0; nt < 3; ++nt) {
        int nn = nt * 16 + c;
        bool valid = (nn < 40);
        #pragma unroll
        for (int kk = 0; kk < 2; ++kk)
            #pragma unroll
            for (int j = 0; j < 8; ++j)
                Bf[nt][kk][j] = valid ? (short)__half_as_ushort(
                    __float2half(W[(kk * 32 + q * 8 + j) * 40 + nn])) : (short)0;
    }
    __syncthreads();

    f32x4 acc[3];
    #pragma unroll
    for (int nt = 0; nt < 3; ++nt) acc[nt] = (f32x4){0.f, 0.f, 0.f, 0.f};
    #pragma unroll
    for (int kk = 0; kk < 2; ++kk) {
        short8 a = *(const short8*)&As[(w * 16 + c) * LDSU + kk * 16 + q * 4];
        #pragma unroll
        for (int nt = 0; nt < 3; ++nt)
            acc[nt] = __builtin_amdgcn_mfma_f32_16x16x32_f16(a, Bf[nt][kk], acc[nt], 0, 0, 0);
    }
    float b2c0 = b2[c];
    float b2c1 = b2[16 + c];
    float b2c2 = (c < 8) ? b2[32 + c] : 0.0f;
    #pragma unroll
    for (int r = 0; r < 4; ++r) {
        int node = nodeBase + w * 16 + q * 4 + r;
        float v0 = acc[0][r] + b2c0;
        float v1 = acc[1][r] + b2c1;
        float v2 = (c < 8) ? acc[2][r] + b2c2 : -INFINITY;
        float mx = fmaxf(fmaxf(v0, v1), v2);
        #pragma unroll
        for (int off = 1; off < 16; off <<= 1) mx = fmaxf(mx, __shfl_xor(mx, off));
        float e = expf(v0 - mx) + expf(v1 - mx) + ((c < 8) ? expf(v2 - mx) : 0.0f);
        #pragma unroll
        for (int off = 1; off < 16; off <<= 1) e += __shfl_xor(e, off);
        float ls = mx + logf(e);
        if (node < n) {
            out[(size_t)node * 40 + c] = v0 - ls;
            out[(size_t)node * 40 + 16 + c] = v1 - ls;
            if (c < 8) out[(size_t)node * 40 + 32 + c] = v2 - ls;
        }
    }
}

extern "C" void kernel_launch(void* const* d_in, const int* in_sizes, int n_in,
                              void* d_out, int out_size, void* d_ws, size_t ws_size,
                              hipStream_t stream) {
    const float* x  = (const float*)d_in[0];
    const int*   ei = (const int*)d_in[1];
    const float* W1 = (const float*)d_in[2];
    const float* b1 = (const float*)d_in[3];
    const float* W2 = (const float*)d_in[4];
    const float* b2 = (const float*)d_in[5];
    float* out = (float*)d_out;

    int N = in_sizes[0] / FIN;     // 100000
    int E = in_sizes[1] / 2;       // 800000
    const int* src = ei;
    const int* dst = ei + E;

    int nbuck = (N + BNODES - 1) / BNODES;   // 1563
    int nblkc = (E + CCHUNK - 1) / CCHUNK;   // 196

    char* ws = (char*)d_ws;
    size_t off = 0;
    auto alloc = [&](size_t bytes) {
        void* p = ws + off;
        off = (off + bytes + 255) & ~(size_t)255;
        return p;
    };
    int*       cnt    = (int*)alloc((size_t)nbuck * nblkc * 4);
    int*       total  = (int*)alloc((size_t)nbuck * 4);
    int*       bstart = (int*)alloc((size_t)(nbuck + 1) * 4);
    unsigned*  ebuf   = (unsigned*)alloc((size_t)E * 4);
    float*     dinv   = (float*)alloc((size_t)N * 4);
    __half*    h1s    = (__half*)alloc((size_t)N * FIN * 2);
    __half*    rs     = (__half*)alloc((size_t)N * HID * 2);
    __half*    sh     = (__half*)alloc((size_t)N * HID * 2);

    int gblocks = (N + 63) / 64;   // 1563

    bucket_hist_kernel<<<nblkc, 256, 0, stream>>>(dst, cnt, E, nbuck, nblkc);
    bucket_colscan_kernel<<<nbuck, 256, 0, stream>>>(cnt, total, nblkc);
    bucket_scan_kernel<<<1, 256, 0, stream>>>(total, bstart, nbuck);
    partition_kernel<<<nblkc, 256, 0, stream>>>(src, dst, cnt, bstart, ebuf, E, nbuck, nblkc);
    dinv_kernel<<<nbuck, 256, 0, stream>>>(ebuf, bstart, dinv, N);
    gemm1_mfma<<<gblocks, 256, 0, stream>>>(x, W1, dinv, h1s, N);
    edge_agg1_kernel<<<nbuck, 256, 0, stream>>>(h1s, ebuf, bstart, dinv, b1, rs, N);
    edge_agg2_kernel<<<nbuck, 256, 0, stream>>>(rs, ebuf, bstart, dinv, sh, N);
    gemm2_softmax<<<gblocks, 256, 0, stream>>>(sh, W2, b2, out, N);
}

// Round 12
// 182.041 us; speedup vs baseline: 4.0701x; 4.0701x over previous
//
#include <hip/hip_runtime.h>
#include <hip/hip_fp16.h>
#include <math.h>

#define FIN 64
#define HID 64
#define FOUT 40
#define H2S_STRIDE 64   // fp16 elements; 128 B row stride, one cache line per row
#define LDSU 36         // uint stride per staged LDS row (144 B): pad breaks conflicts
#define CCHUNK 4096     // edges per partition block
#define MAXBUCK 400     // LDS histogram capacity (>= nbuck = ceil(N/256))

typedef __attribute__((ext_vector_type(8))) short short8;
typedef __attribute__((ext_vector_type(4))) float f32x4;

__device__ __forceinline__ __half2 u2h(unsigned u) { return *(__half2*)&u; }
__device__ __forceinline__ unsigned h2u(__half2 h) { return *(unsigned*)&h; }

// ================= CSR build: two-level counting sort (no global atomics) =================
// bucket = dst >> 8 (256 nodes per bucket). Pack: src (20 bits) | local_dst << 20.

__global__ __launch_bounds__(256) void bucket_hist_kernel(const int* __restrict__ dst,
        int* __restrict__ cnt, int E, int nbuck, int nblkc) {
    __shared__ int hist[MAXBUCK];
    int tid = threadIdx.x;
    for (int i = tid; i < nbuck; i += 256) hist[i] = 0;
    __syncthreads();
    int base = blockIdx.x * CCHUNK;
    int lim = min(CCHUNK, E - base);
    for (int i = tid; i < lim; i += 256)
        atomicAdd(&hist[dst[base + i] >> 8], 1);
    __syncthreads();
    for (int b = tid; b < nbuck; b += 256)
        cnt[b * nblkc + blockIdx.x] = hist[b];
}

__global__ __launch_bounds__(256) void bucket_colscan_kernel(int* __restrict__ cnt,
        int* __restrict__ total, int nblkc) {
    int b = blockIdx.x;
    int tid = threadIdx.x, lane = tid & 63, wid = tid >> 6;
    int v = (tid < nblkc) ? cnt[b * nblkc + tid] : 0;
    int incl = v;
    #pragma unroll
    for (int off = 1; off < 64; off <<= 1) {
        int t2 = __shfl_up(incl, off);
        if (lane >= off) incl += t2;
    }
    __shared__ int ws[4];
    if (lane == 63) ws[wid] = incl;
    __syncthreads();
    int woff = 0;
    for (int w2 = 0; w2 < wid; ++w2) woff += ws[w2];
    int excl = woff + incl - v;
    if (tid < nblkc) cnt[b * nblkc + tid] = excl;
    if (tid == 255) total[b] = woff + incl;
}

__global__ __launch_bounds__(512) void bucket_scan_kernel(const int* __restrict__ total,
        int* __restrict__ bucketStart, int nbuck, int* __restrict__ rowstart, int N) {
    int tid = threadIdx.x, lane = tid & 63, wid = tid >> 6;
    int v = (tid < nbuck) ? total[tid] : 0;
    int incl = v;
    #pragma unroll
    for (int off = 1; off < 64; off <<= 1) {
        int t2 = __shfl_up(incl, off);
        if (lane >= off) incl += t2;
    }
    __shared__ int ws[8];
    if (lane == 63) ws[wid] = incl;
    __syncthreads();
    int woff = 0;
    for (int w2 = 0; w2 < wid; ++w2) woff += ws[w2];
    int excl = woff + incl - v;
    if (tid <= nbuck) bucketStart[tid] = excl;
    if (tid == nbuck) rowstart[N] = excl;     // == E
}

__global__ __launch_bounds__(256) void partition_kernel(const int* __restrict__ src,
        const int* __restrict__ dst, const int* __restrict__ cnt,
        const int* __restrict__ bucketStart, unsigned* __restrict__ ebuf,
        int E, int nbuck, int nblkc) {
    __shared__ int cur[MAXBUCK];
    int tid = threadIdx.x;
    int r = blockIdx.x;
    for (int b = tid; b < nbuck; b += 256)
        cur[b] = bucketStart[b] + cnt[b * nblkc + r];
    __syncthreads();
    int base = r * CCHUNK;
    int lim = min(CCHUNK, E - base);
    for (int i = tid; i < lim; i += 256) {
        int d = dst[base + i];
        int s = src[base + i];
        int b = d >> 8;
        int pos = atomicAdd(&cur[b], 1);       // LDS atomic
        ebuf[pos] = (unsigned)s | ((unsigned)(d & 255) << 20);
    }
}

__global__ __launch_bounds__(256) void build_csr_kernel(const unsigned* __restrict__ ebuf,
        const int* __restrict__ bucketStart, int* __restrict__ rowstart,
        float* __restrict__ dinv, int* __restrict__ csr_src, int n) {
    __shared__ int hist[256];
    __shared__ int cur[256];
    __shared__ int ws[4];
    __shared__ int stage[4096];
    int b = blockIdx.x, tid = threadIdx.x;
    int base = bucketStart[b];
    int m = bucketStart[b + 1] - base;
    hist[tid] = 0;
    __syncthreads();
    for (int i = tid; i < m; i += 256)
        atomicAdd(&hist[ebuf[base + i] >> 20], 1);
    __syncthreads();
    int deg = hist[tid];
    int lane = tid & 63, wid = tid >> 6;
    int incl = deg;
    #pragma unroll
    for (int off = 1; off < 64; off <<= 1) {
        int t2 = __shfl_up(incl, off);
        if (lane >= off) incl += t2;
    }
    if (lane == 63) ws[wid] = incl;
    __syncthreads();
    int woff = 0;
    for (int w2 = 0; w2 < wid; ++w2) woff += ws[w2];
    int excl = woff + incl - deg;
    int node = b * 256 + tid;
    if (node < n) {
        rowstart[node] = base + excl;
        dinv[node] = rsqrtf((float)deg + 1.0f);
    }
    cur[tid] = excl;
    __syncthreads();
    if (m <= 4096) {
        for (int i = tid; i < m; i += 256) {
            unsigned p = ebuf[base + i];
            int pos = atomicAdd(&cur[p >> 20], 1);
            stage[pos] = (int)(p & 0xFFFFFu);
        }
        __syncthreads();
        for (int i = tid; i < m; i += 256)
            csr_src[base + i] = stage[i];      // coalesced
    } else {
        for (int i = tid; i < m; i += 256) {
            unsigned p = ebuf[base + i];
            int pos = atomicAdd(&cur[p >> 20], 1);
            csr_src[base + pos] = (int)(p & 0xFFFFFu);
        }
    }
}

// ================= layer 1 GEMM (MFMA f16): h1s = f16( (x @ W1) * dinv ) =================

__global__ __launch_bounds__(256) void gemm1_mfma(const float* __restrict__ x,
        const float* __restrict__ W, const float* __restrict__ dinv,
        __half* __restrict__ h, int n) {
    __shared__ unsigned As[64 * LDSU];
    int tid = threadIdx.x;
    int lane = tid & 63;
    int w = tid >> 6;
    int q = lane >> 4;        // 0..3 k-block / row-quad
    int c = lane & 15;        // col within tile
    int nodeBase = blockIdx.x * 64;

    #pragma unroll
    for (int i = 0; i < 4; ++i) {
        int fidx = tid + 256 * i;          // float4 index 0..1023
        int row = fidx >> 4, c4 = fidx & 15;
        int node = nodeBase + row; if (node >= n) node = n - 1;
        float4 v = *(const float4*)(x + (size_t)node * 64 + c4 * 4);
        As[row * LDSU + c4 * 2 + 0] = h2u(__floats2half2_rn(v.x, v.y));
        As[row * LDSU + c4 * 2 + 1] = h2u(__floats2half2_rn(v.z, v.w));
    }
    short8 Bf[4][2];
    #pragma unroll
    for (int nt = 0; nt < 4; ++nt)
        #pragma unroll
        for (int kk = 0; kk < 2; ++kk)
            #pragma unroll
            for (int j = 0; j < 8; ++j)
                Bf[nt][kk][j] = (short)__half_as_ushort(
                    __float2half(W[(kk * 32 + q * 8 + j) * 64 + nt * 16 + c]));
    __syncthreads();

    f32x4 acc[4];
    #pragma unroll
    for (int nt = 0; nt < 4; ++nt) acc[nt] = (f32x4){0.f, 0.f, 0.f, 0.f};
    #pragma unroll
    for (int kk = 0; kk < 2; ++kk) {
        short8 a = *(const short8*)&As[(w * 16 + c) * LDSU + kk * 16 + q * 4];
        #pragma unroll
        for (int nt = 0; nt < 4; ++nt)
            acc[nt] = __builtin_amdgcn_mfma_f32_16x16x32_f16(a, Bf[nt][kk], acc[nt], 0, 0, 0);
    }
    unsigned short* hu = (unsigned short*)h;
    #pragma unroll
    for (int r = 0; r < 4; ++r) {
        int node = nodeBase + w * 16 + q * 4 + r;
        if (node < n) {
            float dv = dinv[node];
            #pragma unroll
            for (int nt = 0; nt < 4; ++nt)
                hu[(size_t)node * 64 + nt * 16 + c] =
                    __half_as_ushort(__float2half(acc[nt][r] * dv));
        }
    }
}

// ================= gather layer 1: 4 nodes per wave (one per quarter) =================
// Quarter q owns node base+q; its 16 lanes hold the full 128 B row (uint2/lane).
// csr ids batch-prefetched 8 at a time by lanes i4<8, broadcast via __shfl.
// No cross-quarter combine. agg1h[d] = f16( relu( dinv*(sum + h1s[d]) + b1 ) * dinv ).

__global__ __launch_bounds__(256) void gather1_kernel(const __half* __restrict__ h1s,
        const int* __restrict__ rowstart, const int* __restrict__ csr_src,
        const float* __restrict__ dinv, const float* __restrict__ b,
        __half* __restrict__ agg1, int n) {
    int tid = threadIdx.x;
    int lane = tid & 63;
    int wid = tid >> 6;
    int q = lane >> 4;            // quarter = which of the wave's 4 nodes
    int i4 = lane & 15;           // uint2 index within row (features 4*i4..4*i4+3)
    int node = blockIdx.x * 16 + wid * 4 + q;
    bool valid = (node < n);
    int nodec = valid ? node : (n - 1);
    int beg = rowstart[nodec];
    int end = valid ? rowstart[nodec + 1] : beg;
    int deg = end - beg;
    int maxdeg = deg;
    #pragma unroll
    for (int off = 1; off < 64; off <<= 1) maxdeg = max(maxdeg, __shfl_xor(maxdeg, off));
    const uint2* hv = (const uint2*)h1s;
    __half2 ax = u2h(0u), ay = u2h(0u);
    for (int bj = 0; bj < maxdeg; bj += 8) {
        int idx = beg + bj + i4;
        int sid = (i4 < 8 && bj + i4 < deg) ? csr_src[idx] : 0;
        #pragma unroll
        for (int j = 0; j < 8; ++j) {
            int s = __shfl(sid, (q << 4) + j);    // broadcast within quarter
            if (bj + j < deg) {
                uint2 v = hv[(size_t)s * 16 + i4];
                ax = __hadd2(ax, u2h(v.x));
                ay = __hadd2(ay, u2h(v.y));
            }
        }
    }
    uint2 u_self = hv[(size_t)nodec * 16 + i4];
    float2 fx = __half22float2(ax);
    float2 fy = __half22float2(ay);
    float2 sx = __half22float2(u2h(u_self.x));
    float2 sy = __half22float2(u2h(u_self.y));
    float dv = dinv[nodec];
    float4 bb = *(const float4*)(b + 4 * i4);
    float v0 = fmaxf((fx.x + sx.x) * dv + bb.x, 0.0f) ;
    float v1 = fmaxf((fx.y + sx.y) * dv + bb.y, 0.0f);
    float v2 = fmaxf((fy.x + sy.x) * dv + bb.z, 0.0f);
    float v3 = fmaxf((fy.y + sy.y) * dv + bb.w, 0.0f);
    if (valid) {
        uint2 o;
        o.x = h2u(__floats2half2_rn(v0, v1));
        o.y = h2u(__floats2half2_rn(v2, v3));
        ((uint2*)agg1)[(size_t)node * 16 + i4] = o;
    }
}

// ================= layer 2 GEMM (MFMA f16): h2s = f16( (agg1h @ W2) * dinv ) =================

__global__ __launch_bounds__(256) void gemm2_mfma(const __half* __restrict__ agg1h,
        const float* __restrict__ W, const float* __restrict__ dinv,
        __half* __restrict__ h2, int n) {
    __shared__ unsigned As[64 * LDSU];
    int tid = threadIdx.x;
    int lane = tid & 63;
    int w = tid >> 6;
    int q = lane >> 4;
    int c = lane & 15;
    int nodeBase = blockIdx.x * 64;
    const unsigned* a1u = (const unsigned*)agg1h;

    #pragma unroll
    for (int i = 0; i < 8; ++i) {
        int uidx = tid + 256 * i;          // 0..2047
        int row = uidx >> 5, col = uidx & 31;
        int node = nodeBase + row; if (node >= n) node = n - 1;
        As[row * LDSU + col] = a1u[(size_t)node * 32 + col];
    }
    short8 Bf[3][2];
    #pragma unroll
    for (int nt = 0; nt < 3; ++nt) {
        int nn = nt * 16 + c;
        bool valid = (nn < 40);
        #pragma unroll
        for (int kk = 0; kk < 2; ++kk)
            #pragma unroll
            for (int j = 0; j < 8; ++j)
                Bf[nt][kk][j] = valid ? (short)__half_as_ushort(
                    __float2half(W[(kk * 32 + q * 8 + j) * 40 + nn])) : (short)0;
    }
    __syncthreads();

    f32x4 acc[3];
    #pragma unroll
    for (int nt = 0; nt < 3; ++nt) acc[nt] = (f32x4){0.f, 0.f, 0.f, 0.f};
    #pragma unroll
    for (int kk = 0; kk < 2; ++kk) {
        short8 a = *(const short8*)&As[(w * 16 + c) * LDSU + kk * 16 + q * 4];
        #pragma unroll
        for (int nt = 0; nt < 3; ++nt)
            acc[nt] = __builtin_amdgcn_mfma_f32_16x16x32_f16(a, Bf[nt][kk], acc[nt], 0, 0, 0);
    }
    unsigned short* hu = (unsigned short*)h2;
    #pragma unroll
    for (int r = 0; r < 4; ++r) {
        int node = nodeBase + w * 16 + q * 4 + r;
        if (node < n) {
            float dv = dinv[node];
            #pragma unroll
            for (int nt = 0; nt < 3; ++nt) {
                int nn = nt * 16 + c;
                if (nn < 40)
                    hu[(size_t)node * H2S_STRIDE + nn] =
                        __half_as_ushort(__float2half(acc[nt][r] * dv));
            }
        }
    }
}

// ================= gather layer 2 + fused log_softmax: 4 nodes per wave =================
// Quarter q owns its node fully; row reduction for softmax = shfl_xor 1/2/4/8
// (stays within the 16-lane quarter). Lanes i4<10 hold the 40 valid features.

__global__ __launch_bounds__(256) void gather2_kernel(const __half* __restrict__ h2s,
        const int* __restrict__ rowstart, const int* __restrict__ csr_src,
        const float* __restrict__ dinv, const float* __restrict__ b,
        float* __restrict__ out, int n) {
    int tid = threadIdx.x;
    int lane = tid & 63;
    int wid = tid >> 6;
    int q = lane >> 4;
    int i4 = lane & 15;
    int ic = (i4 < 10) ? i4 : 9;   // clamp into valid 40-feature region (same line)
    int node = blockIdx.x * 16 + wid * 4 + q;
    bool valid = (node < n);
    int nodec = valid ? node : (n - 1);
    int beg = rowstart[nodec];
    int end = valid ? rowstart[nodec + 1] : beg;
    int deg = end - beg;
    int maxdeg = deg;
    #pragma unroll
    for (int off = 1; off < 64; off <<= 1) maxdeg = max(maxdeg, __shfl_xor(maxdeg, off));
    const uint2* hv = (const uint2*)h2s;
    __half2 ax = u2h(0u), ay = u2h(0u);
    for (int bj = 0; bj < maxdeg; bj += 8) {
        int idx = beg + bj + i4;
        int sid = (i4 < 8 && bj + i4 < deg) ? csr_src[idx] : 0;
        #pragma unroll
        for (int j = 0; j < 8; ++j) {
            int s = __shfl(sid, (q << 4) + j);
            if (bj + j < deg) {
                uint2 v = hv[(size_t)s * 16 + ic];
                ax = __hadd2(ax, u2h(v.x));
                ay = __hadd2(ay, u2h(v.y));
            }
        }
    }
    uint2 u_self = hv[(size_t)nodec * 16 + ic];
    float2 fx = __half22float2(ax);
    float2 fy = __half22float2(ay);
    float2 sx = __half22float2(u2h(u_self.x));
    float2 sy = __half22float2(u2h(u_self.y));
    float dv = dinv[nodec];
    float4 bb = *(const float4*)(b + 4 * ic);
    float v0 = (fx.x + sx.x) * dv + bb.x;
    float v1 = (fx.y + sx.y) * dv + bb.y;
    float v2 = (fy.x + sy.x) * dv + bb.z;
    float v3 = (fy.y + sy.y) * dv + bb.w;
    // log_softmax over the quarter's 40 features (lanes i4<10 each hold 4)
    bool act = (i4 < 10);
    float mx = act ? fmaxf(fmaxf(v0, v1), fmaxf(v2, v3)) : -INFINITY;
    #pragma unroll
    for (int off = 1; off < 16; off <<= 1) mx = fmaxf(mx, __shfl_xor(mx, off));
    float sm = act ? (expf(v0 - mx) + expf(v1 - mx) + expf(v2 - mx) + expf(v3 - mx)) : 0.0f;
    #pragma unroll
    for (int off = 1; off < 16; off <<= 1) sm += __shfl_xor(sm, off);
    float ls = mx + logf(sm);
    if (valid && act)
        *(float4*)(out + (size_t)node * 40 + 4 * i4) =
            make_float4(v0 - ls, v1 - ls, v2 - ls, v3 - ls);
}

extern "C" void kernel_launch(void* const* d_in, const int* in_sizes, int n_in,
                              void* d_out, int out_size, void* d_ws, size_t ws_size,
                              hipStream_t stream) {
    const float* x  = (const float*)d_in[0];
    const int*   ei = (const int*)d_in[1];
    const float* W1 = (const float*)d_in[2];
    const float* b1 = (const float*)d_in[3];
    const float* W2 = (const float*)d_in[4];
    const float* b2 = (const float*)d_in[5];
    float* out = (float*)d_out;

    int N = in_sizes[0] / FIN;     // 100000
    int E = in_sizes[1] / 2;       // 800000
    const int* src = ei;
    const int* dst = ei + E;

    int nbuck = (N + 255) >> 8;              // 391
    int nblkc = (E + CCHUNK - 1) / CCHUNK;   // 196

    char* ws = (char*)d_ws;
    size_t off = 0;
    auto alloc = [&](size_t bytes) {
        void* p = ws + off;
        off = (off + bytes + 255) & ~(size_t)255;
        return p;
    };
    int*       cnt       = (int*)alloc((size_t)nbuck * nblkc * 4);
    int*       total     = (int*)alloc((size_t)nbuck * 4);
    int*       bstart    = (int*)alloc((size_t)(nbuck + 1) * 4);
    unsigned*  ebuf      = (unsigned*)alloc((size_t)E * 4);
    int*       rowstart  = (int*)alloc((size_t)(N + 1) * 4);
    float*     dinv      = (float*)alloc((size_t)N * 4);
    int*       csr_src   = (int*)alloc((size_t)E * 4);
    __half*    h1s       = (__half*)alloc((size_t)N * FIN * 2);
    __half*    agg1h     = (__half*)alloc((size_t)N * HID * 2);
    __half*    h2s       = (__half*)alloc((size_t)N * H2S_STRIDE * 2);

    int gblocks = (N + 63) / 64;     // 1563
    int gablocks = (N + 15) / 16;    // 6250

    bucket_hist_kernel<<<nblkc, 256, 0, stream>>>(dst, cnt, E, nbuck, nblkc);
    bucket_colscan_kernel<<<nbuck, 256, 0, stream>>>(cnt, total, nblkc);
    bucket_scan_kernel<<<1, 512, 0, stream>>>(total, bstart, nbuck, rowstart, N);
    partition_kernel<<<nblkc, 256, 0, stream>>>(src, dst, cnt, bstart, ebuf, E, nbuck, nblkc);
    build_csr_kernel<<<nbuck, 256, 0, stream>>>(ebuf, bstart, rowstart, dinv, csr_src, N);
    gemm1_mfma<<<gblocks, 256, 0, stream>>>(x, W1, dinv, h1s, N);
    gather1_kernel<<<gablocks, 256, 0, stream>>>(h1s, rowstart, csr_src, dinv, b1, agg1h, N);
    gemm2_mfma<<<gblocks, 256, 0, stream>>>(agg1h, W2, dinv, h2s, N);
    gather2_kernel<<<gablocks, 256, 0, stream>>>(h2s, rowstart, csr_src, dinv, b2, out, N);
}

// Round 13
// 174.012 us; speedup vs baseline: 4.2579x; 1.0461x over previous
//
#include <hip/hip_runtime.h>
#include <hip/hip_fp16.h>
#include <math.h>

#define FIN 64
#define HID 64
#define FOUT 40
#define H2S_STRIDE 64   // fp16 elements; 128 B row stride, one cache line per row
#define LDSU 36         // uint stride per staged LDS row (144 B): pad breaks conflicts
#define CCHUNK 4096     // edges per partition block
#define MAXBUCK 400     // LDS histogram capacity (>= nbuck = ceil(N/256))

typedef __attribute__((ext_vector_type(8))) short short8;
typedef __attribute__((ext_vector_type(4))) float f32x4;

__device__ __forceinline__ __half2 u2h(unsigned u) { return *(__half2*)&u; }
__device__ __forceinline__ unsigned h2u(__half2 h) { return *(unsigned*)&h; }
__device__ __forceinline__ __half2 shfl_xor_h2(__half2 v, int off) {
    int b = *(int*)&v;
    b = __shfl_xor(b, off);
    return *(__half2*)&b;
}

// ================= CSR build: two-level counting sort (no global atomics) =================
// bucket = dst >> 8 (256 nodes per bucket). Pack: src (20 bits) | local_dst << 20.

__global__ __launch_bounds__(256) void bucket_hist_kernel(const int* __restrict__ dst,
        int* __restrict__ cnt, int E, int nbuck, int nblkc) {
    __shared__ int hist[MAXBUCK];
    int tid = threadIdx.x;
    for (int i = tid; i < nbuck; i += 256) hist[i] = 0;
    __syncthreads();
    int base = blockIdx.x * CCHUNK;
    int lim = min(CCHUNK, E - base);
    for (int i = tid; i < lim; i += 256)
        atomicAdd(&hist[dst[base + i] >> 8], 1);
    __syncthreads();
    for (int b = tid; b < nbuck; b += 256)
        cnt[b * nblkc + blockIdx.x] = hist[b];
}

__global__ __launch_bounds__(256) void bucket_colscan_kernel(int* __restrict__ cnt,
        int* __restrict__ total, int nblkc) {
    int b = blockIdx.x;
    int tid = threadIdx.x, lane = tid & 63, wid = tid >> 6;
    int v = (tid < nblkc) ? cnt[b * nblkc + tid] : 0;
    int incl = v;
    #pragma unroll
    for (int off = 1; off < 64; off <<= 1) {
        int t2 = __shfl_up(incl, off);
        if (lane >= off) incl += t2;
    }
    __shared__ int ws[4];
    if (lane == 63) ws[wid] = incl;
    __syncthreads();
    int woff = 0;
    for (int w2 = 0; w2 < wid; ++w2) woff += ws[w2];
    int excl = woff + incl - v;
    if (tid < nblkc) cnt[b * nblkc + tid] = excl;
    if (tid == 255) total[b] = woff + incl;
}

__global__ __launch_bounds__(512) void bucket_scan_kernel(const int* __restrict__ total,
        int* __restrict__ bucketStart, int nbuck, int* __restrict__ rowstart, int N) {
    int tid = threadIdx.x, lane = tid & 63, wid = tid >> 6;
    int v = (tid < nbuck) ? total[tid] : 0;
    int incl = v;
    #pragma unroll
    for (int off = 1; off < 64; off <<= 1) {
        int t2 = __shfl_up(incl, off);
        if (lane >= off) incl += t2;
    }
    __shared__ int ws[8];
    if (lane == 63) ws[wid] = incl;
    __syncthreads();
    int woff = 0;
    for (int w2 = 0; w2 < wid; ++w2) woff += ws[w2];
    int excl = woff + incl - v;
    if (tid <= nbuck) bucketStart[tid] = excl;
    if (tid == nbuck) rowstart[N] = excl;     // == E
}

__global__ __launch_bounds__(256) void partition_kernel(const int* __restrict__ src,
        const int* __restrict__ dst, const int* __restrict__ cnt,
        const int* __restrict__ bucketStart, unsigned* __restrict__ ebuf,
        int E, int nbuck, int nblkc) {
    __shared__ int cur[MAXBUCK];
    int tid = threadIdx.x;
    int r = blockIdx.x;
    for (int b = tid; b < nbuck; b += 256)
        cur[b] = bucketStart[b] + cnt[b * nblkc + r];
    __syncthreads();
    int base = r * CCHUNK;
    int lim = min(CCHUNK, E - base);
    for (int i = tid; i < lim; i += 256) {
        int d = dst[base + i];
        int s = src[base + i];
        int b = d >> 8;
        int pos = atomicAdd(&cur[b], 1);       // LDS atomic
        ebuf[pos] = (unsigned)s | ((unsigned)(d & 255) << 20);
    }
}

__global__ __launch_bounds__(256) void build_csr_kernel(const unsigned* __restrict__ ebuf,
        const int* __restrict__ bucketStart, int* __restrict__ rowstart,
        float* __restrict__ dinv, int* __restrict__ csr_src, int n) {
    __shared__ int hist[256];
    __shared__ int cur[256];
    __shared__ int ws[4];
    __shared__ int stage[4096];
    int b = blockIdx.x, tid = threadIdx.x;
    int base = bucketStart[b];
    int m = bucketStart[b + 1] - base;
    hist[tid] = 0;
    __syncthreads();
    for (int i = tid; i < m; i += 256)
        atomicAdd(&hist[ebuf[base + i] >> 20], 1);
    __syncthreads();
    int deg = hist[tid];
    int lane = tid & 63, wid = tid >> 6;
    int incl = deg;
    #pragma unroll
    for (int off = 1; off < 64; off <<= 1) {
        int t2 = __shfl_up(incl, off);
        if (lane >= off) incl += t2;
    }
    if (lane == 63) ws[wid] = incl;
    __syncthreads();
    int woff = 0;
    for (int w2 = 0; w2 < wid; ++w2) woff += ws[w2];
    int excl = woff + incl - deg;
    int node = b * 256 + tid;
    if (node < n) {
        rowstart[node] = base + excl;
        dinv[node] = rsqrtf((float)deg + 1.0f);
    }
    cur[tid] = excl;
    __syncthreads();
    if (m <= 4096) {
        for (int i = tid; i < m; i += 256) {
            unsigned p = ebuf[base + i];
            int pos = atomicAdd(&cur[p >> 20], 1);
            stage[pos] = (int)(p & 0xFFFFFu);
        }
        __syncthreads();
        for (int i = tid; i < m; i += 256)
            csr_src[base + i] = stage[i];      // coalesced
    } else {
        for (int i = tid; i < m; i += 256) {
            unsigned p = ebuf[base + i];
            int pos = atomicAdd(&cur[p >> 20], 1);
            csr_src[base + pos] = (int)(p & 0xFFFFFu);
        }
    }
}

// ================= layer 1 GEMM (MFMA f16): h1s = f16( (x @ W1) * dinv ) =================

__global__ __launch_bounds__(256) void gemm1_mfma(const float* __restrict__ x,
        const float* __restrict__ W, const float* __restrict__ dinv,
        __half* __restrict__ h, int n) {
    __shared__ unsigned As[64 * LDSU];
    int tid = threadIdx.x;
    int lane = tid & 63;
    int w = tid >> 6;
    int q = lane >> 4;        // 0..3 k-block / row-quad
    int c = lane & 15;        // col within tile
    int nodeBase = blockIdx.x * 64;

    #pragma unroll
    for (int i = 0; i < 4; ++i) {
        int fidx = tid + 256 * i;          // float4 index 0..1023
        int row = fidx >> 4, c4 = fidx & 15;
        int node = nodeBase + row; if (node >= n) node = n - 1;
        float4 v = *(const float4*)(x + (size_t)node * 64 + c4 * 4);
        As[row * LDSU + c4 * 2 + 0] = h2u(__floats2half2_rn(v.x, v.y));
        As[row * LDSU + c4 * 2 + 1] = h2u(__floats2half2_rn(v.z, v.w));
    }
    short8 Bf[4][2];
    #pragma unroll
    for (int nt = 0; nt < 4; ++nt)
        #pragma unroll
        for (int kk = 0; kk < 2; ++kk)
            #pragma unroll
            for (int j = 0; j < 8; ++j)
                Bf[nt][kk][j] = (short)__half_as_ushort(
                    __float2half(W[(kk * 32 + q * 8 + j) * 64 + nt * 16 + c]));
    __syncthreads();

    f32x4 acc[4];
    #pragma unroll
    for (int nt = 0; nt < 4; ++nt) acc[nt] = (f32x4){0.f, 0.f, 0.f, 0.f};
    #pragma unroll
    for (int kk = 0; kk < 2; ++kk) {
        short8 a = *(const short8*)&As[(w * 16 + c) * LDSU + kk * 16 + q * 4];
        #pragma unroll
        for (int nt = 0; nt < 4; ++nt)
            acc[nt] = __builtin_amdgcn_mfma_f32_16x16x32_f16(a, Bf[nt][kk], acc[nt], 0, 0, 0);
    }
    unsigned short* hu = (unsigned short*)h;
    #pragma unroll
    for (int r = 0; r < 4; ++r) {
        int node = nodeBase + w * 16 + q * 4 + r;
        if (node < n) {
            float dv = dinv[node];
            #pragma unroll
            for (int nt = 0; nt < 4; ++nt)
                hu[(size_t)node * 64 + nt * 16 + c] =
                    __half_as_ushort(__float2half(acc[nt][r] * dv));
        }
    }
}

// ================= gather layer 1: 4 nodes/wave, uint4 loads (2 edges per quarter-instr) ====
// Quarter q owns node base+q. Octet o (8 lanes) covers one edge's 128 B row as uint4;
// the two octets of a quarter cover edges e and e+1 in ONE load instruction.
// csr ids batch-prefetched 8 at a time by lanes i4<8, broadcast via __shfl.
// End: one shfl_xor(8) octet combine. agg1h[d] = f16( relu( dinv*(sum+self) + b1 ) ).

__global__ __launch_bounds__(256) void gather1_kernel(const __half* __restrict__ h1s,
        const int* __restrict__ rowstart, const int* __restrict__ csr_src,
        const float* __restrict__ dinv, const float* __restrict__ b,
        __half* __restrict__ agg1, int n) {
    int tid = threadIdx.x;
    int lane = tid & 63;
    int wid = tid >> 6;
    int q = lane >> 4;            // quarter = which of the wave's 4 nodes
    int i4 = lane & 15;
    int o = i4 >> 3;              // octet: edge parity within the pair
    int f8 = i4 & 7;              // uint4 index within 128 B row
    int node = blockIdx.x * 16 + wid * 4 + q;
    bool valid = (node < n);
    int nodec = valid ? node : (n - 1);
    int beg = rowstart[nodec];
    int end = valid ? rowstart[nodec + 1] : beg;
    int deg = end - beg;
    int maxdeg = deg;
    #pragma unroll
    for (int off = 1; off < 64; off <<= 1) maxdeg = max(maxdeg, __shfl_xor(maxdeg, off));
    const uint4* hv = (const uint4*)h1s;   // 8 uint4 per row
    __half2 a0 = u2h(0u), a1 = u2h(0u), a2 = u2h(0u), a3 = u2h(0u);
    for (int bj = 0; bj < maxdeg; bj += 8) {
        int idx = beg + bj + i4;
        int sid = (i4 < 8 && bj + i4 < deg) ? csr_src[idx] : 0;
        #pragma unroll
        for (int j = 0; j < 4; ++j) {
            int e = 2 * j + o;
            int s = __shfl(sid, (q << 4) + e);    // broadcast within quarter
            if (bj + e < deg) {
                uint4 v = hv[(size_t)s * 8 + f8];
                a0 = __hadd2(a0, u2h(v.x));
                a1 = __hadd2(a1, u2h(v.y));
                a2 = __hadd2(a2, u2h(v.z));
                a3 = __hadd2(a3, u2h(v.w));
            }
        }
    }
    // combine the octet pair (edges e / e+1)
    a0 = __hadd2(a0, shfl_xor_h2(a0, 8));
    a1 = __hadd2(a1, shfl_xor_h2(a1, 8));
    a2 = __hadd2(a2, shfl_xor_h2(a2, 8));
    a3 = __hadd2(a3, shfl_xor_h2(a3, 8));
    uint4 us = hv[(size_t)nodec * 8 + f8];
    float2 s0 = __half22float2(u2h(us.x)), s1 = __half22float2(u2h(us.y));
    float2 s2 = __half22float2(u2h(us.z)), s3 = __half22float2(u2h(us.w));
    float2 f0 = __half22float2(a0), f1 = __half22float2(a1);
    float2 f2 = __half22float2(a2), f3 = __half22float2(a3);
    float dv = dinv[nodec];
    float4 bb0 = *(const float4*)(b + 8 * f8);
    float4 bb1 = *(const float4*)(b + 8 * f8 + 4);
    float v0 = fmaxf((f0.x + s0.x) * dv + bb0.x, 0.0f);
    float v1 = fmaxf((f0.y + s0.y) * dv + bb0.y, 0.0f);
    float v2 = fmaxf((f1.x + s1.x) * dv + bb0.z, 0.0f);
    float v3 = fmaxf((f1.y + s1.y) * dv + bb0.w, 0.0f);
    float v4 = fmaxf((f2.x + s2.x) * dv + bb1.x, 0.0f);
    float v5 = fmaxf((f2.y + s2.y) * dv + bb1.y, 0.0f);
    float v6 = fmaxf((f3.x + s3.x) * dv + bb1.z, 0.0f);
    float v7 = fmaxf((f3.y + s3.y) * dv + bb1.w, 0.0f);
    if (valid && o == 0) {
        uint4 out4;
        out4.x = h2u(__floats2half2_rn(v0, v1));
        out4.y = h2u(__floats2half2_rn(v2, v3));
        out4.z = h2u(__floats2half2_rn(v4, v5));
        out4.w = h2u(__floats2half2_rn(v6, v7));
        ((uint4*)agg1)[(size_t)node * 8 + f8] = out4;
    }
}

// ================= layer 2 GEMM (MFMA f16): h2s = f16( (agg1h @ W2) * dinv ) =================

__global__ __launch_bounds__(256) void gemm2_mfma(const __half* __restrict__ agg1h,
        const float* __restrict__ W, const float* __restrict__ dinv,
        __half* __restrict__ h2, int n) {
    __shared__ unsigned As[64 * LDSU];
    int tid = threadIdx.x;
    int lane = tid & 63;
    int w = tid >> 6;
    int q = lane >> 4;
    int c = lane & 15;
    int nodeBase = blockIdx.x * 64;
    const unsigned* a1u = (const unsigned*)agg1h;

    #pragma unroll
    for (int i = 0; i < 8; ++i) {
        int uidx = tid + 256 * i;          // 0..2047
        int row = uidx >> 5, col = uidx & 31;
        int node = nodeBase + row; if (node >= n) node = n - 1;
        As[row * LDSU + col] = a1u[(size_t)node * 32 + col];
    }
    short8 Bf[3][2];
    #pragma unroll
    for (int nt = 0; nt < 3; ++nt) {
        int nn = nt * 16 + c;
        bool valid = (nn < 40);
        #pragma unroll
        for (int kk = 0; kk < 2; ++kk)
            #pragma unroll
            for (int j = 0; j < 8; ++j)
                Bf[nt][kk][j] = valid ? (short)__half_as_ushort(
                    __float2half(W[(kk * 32 + q * 8 + j) * 40 + nn])) : (short)0;
    }
    __syncthreads();

    f32x4 acc[3];
    #pragma unroll
    for (int nt = 0; nt < 3; ++nt) acc[nt] = (f32x4){0.f, 0.f, 0.f, 0.f};
    #pragma unroll
    for (int kk = 0; kk < 2; ++kk) {
        short8 a = *(const short8*)&As[(w * 16 + c) * LDSU + kk * 16 + q * 4];
        #pragma unroll
        for (int nt = 0; nt < 3; ++nt)
            acc[nt] = __builtin_amdgcn_mfma_f32_16x16x32_f16(a, Bf[nt][kk], acc[nt], 0, 0, 0);
    }
    unsigned short* hu = (unsigned short*)h2;
    #pragma unroll
    for (int r = 0; r < 4; ++r) {
        int node = nodeBase + w * 16 + q * 4 + r;
        if (node < n) {
            float dv = dinv[node];
            #pragma unroll
            for (int nt = 0; nt < 3; ++nt) {
                int nn = nt * 16 + c;
                if (nn < 40)
                    hu[(size_t)node * H2S_STRIDE + nn] =
                        __half_as_ushort(__float2half(acc[nt][r] * dv));
            }
        }
    }
}

// ================= gather layer 2 + fused log_softmax: 4 nodes/wave, uint4 loads =========
// Row = 40 fp16 in 128 B stride; uint4 index f8<5 holds the valid 40 features
// (f8>=5 clamps to 4 and is masked). Octet pair covers 2 edges per load instr;
// softmax reduction = shfl_xor 1/2/4 within the octet (act lanes f8<5 only).

__global__ __launch_bounds__(256) void gather2_kernel(const __half* __restrict__ h2s,
        const int* __restrict__ rowstart, const int* __restrict__ csr_src,
        const float* __restrict__ dinv, const float* __restrict__ b,
        float* __restrict__ out, int n) {
    int tid = threadIdx.x;
    int lane = tid & 63;
    int wid = tid >> 6;
    int q = lane >> 4;
    int i4 = lane & 15;
    int o = i4 >> 3;
    int f8 = i4 & 7;
    int f8c = (f8 < 5) ? f8 : 4;   // clamp into valid 40-feature region (same line)
    int node = blockIdx.x * 16 + wid * 4 + q;
    bool valid = (node < n);
    int nodec = valid ? node : (n - 1);
    int beg = rowstart[nodec];
    int end = valid ? rowstart[nodec + 1] : beg;
    int deg = end - beg;
    int maxdeg = deg;
    #pragma unroll
    for (int off = 1; off < 64; off <<= 1) maxdeg = max(maxdeg, __shfl_xor(maxdeg, off));
    const uint4* hv = (const uint4*)h2s;   // 8 uint4 per padded row
    __half2 a0 = u2h(0u), a1 = u2h(0u), a2 = u2h(0u), a3 = u2h(0u);
    for (int bj = 0; bj < maxdeg; bj += 8) {
        int idx = beg + bj + i4;
        int sid = (i4 < 8 && bj + i4 < deg) ? csr_src[idx] : 0;
        #pragma unroll
        for (int j = 0; j < 4; ++j) {
            int e = 2 * j + o;
            int s = __shfl(sid, (q << 4) + e);
            if (bj + e < deg) {
                uint4 v = hv[(size_t)s * 8 + f8c];
                a0 = __hadd2(a0, u2h(v.x));
                a1 = __hadd2(a1, u2h(v.y));
                a2 = __hadd2(a2, u2h(v.z));
                a3 = __hadd2(a3, u2h(v.w));
            }
        }
    }
    a0 = __hadd2(a0, shfl_xor_h2(a0, 8));
    a1 = __hadd2(a1, shfl_xor_h2(a1, 8));
    a2 = __hadd2(a2, shfl_xor_h2(a2, 8));
    a3 = __hadd2(a3, shfl_xor_h2(a3, 8));
    uint4 us = hv[(size_t)nodec * 8 + f8c];
    float2 s0 = __half22float2(u2h(us.x)), s1 = __half22float2(u2h(us.y));
    float2 s2 = __half22float2(u2h(us.z)), s3 = __half22float2(u2h(us.w));
    float2 f0 = __half22float2(a0), f1 = __half22float2(a1);
    float2 f2 = __half22float2(a2), f3 = __half22float2(a3);
    float dv = dinv[nodec];
    float4 bb0 = *(const float4*)(b + 8 * f8c);
    float4 bb1 = *(const float4*)(b + 8 * f8c + 4);
    float v0 = (f0.x + s0.x) * dv + bb0.x;
    float v1 = (f0.y + s0.y) * dv + bb0.y;
    float v2 = (f1.x + s1.x) * dv + bb0.z;
    float v3 = (f1.y + s1.y) * dv + bb0.w;
    float v4 = (f2.x + s2.x) * dv + bb1.x;
    float v5 = (f2.y + s2.y) * dv + bb1.y;
    float v6 = (f3.x + s3.x) * dv + bb1.z;
    float v7 = (f3.y + s3.y) * dv + bb1.w;
    // log_softmax over 40 features: valid lanes f8<5 each hold 8 distinct features;
    // reduction stays within the octet (shfl_xor 1/2/4 over f8).
    bool act = (f8 < 5);
    float mx = act ? fmaxf(fmaxf(fmaxf(v0, v1), fmaxf(v2, v3)),
                           fmaxf(fmaxf(v4, v5), fmaxf(v6, v7))) : -INFINITY;
    #pragma unroll
    for (int off = 1; off < 8; off <<= 1) mx = fmaxf(mx, __shfl_xor(mx, off));
    float sm = act ? (expf(v0 - mx) + expf(v1 - mx) + expf(v2 - mx) + expf(v3 - mx) +
                      expf(v4 - mx) + expf(v5 - mx) + expf(v6 - mx) + expf(v7 - mx)) : 0.0f;
    #pragma unroll
    for (int off = 1; off < 8; off <<= 1) sm += __shfl_xor(sm, off);
    float ls = mx + logf(sm);
    if (valid && act && o == 0) {
        *(float4*)(out + (size_t)node * 40 + 8 * f8) =
            make_float4(v0 - ls, v1 - ls, v2 - ls, v3 - ls);
        *(float4*)(out + (size_t)node * 40 + 8 * f8 + 4) =
            make_float4(v4 - ls, v5 - ls, v6 - ls, v7 - ls);
    }
}

extern "C" void kernel_launch(void* const* d_in, const int* in_sizes, int n_in,
                              void* d_out, int out_size, void* d_ws, size_t ws_size,
                              hipStream_t stream) {
    const float* x  = (const float*)d_in[0];
    const int*   ei = (const int*)d_in[1];
    const float* W1 = (const float*)d_in[2];
    const float* b1 = (const float*)d_in[3];
    const float* W2 = (const float*)d_in[4];
    const float* b2 = (const float*)d_in[5];
    float* out = (float*)d_out;

    int N = in_sizes[0] / FIN;     // 100000
    int E = in_sizes[1] / 2;       // 800000
    const int* src = ei;
    const int* dst = ei + E;

    int nbuck = (N + 255) >> 8;              // 391
    int nblkc = (E + CCHUNK - 1) / CCHUNK;   // 196

    char* ws = (char*)d_ws;
    size_t off = 0;
    auto alloc = [&](size_t bytes) {
        void* p = ws + off;
        off = (off + bytes + 255) & ~(size_t)255;
        return p;
    };
    int*       cnt       = (int*)alloc((size_t)nbuck * nblkc * 4);
    int*       total     = (int*)alloc((size_t)nbuck * 4);
    int*       bstart    = (int*)alloc((size_t)(nbuck + 1) * 4);
    unsigned*  ebuf      = (unsigned*)alloc((size_t)E * 4);
    int*       rowstart  = (int*)alloc((size_t)(N + 1) * 4);
    float*     dinv      = (float*)alloc((size_t)N * 4);
    int*       csr_src   = (int*)alloc((size_t)E * 4);
    __half*    h1s       = (__half*)alloc((size_t)N * FIN * 2);
    __half*    agg1h     = (__half*)alloc((size_t)N * HID * 2);
    __half*    h2s       = (__half*)alloc((size_t)N * H2S_STRIDE * 2);

    int gblocks = (N + 63) / 64;     // 1563
    int gablocks = (N + 15) / 16;    // 6250

    bucket_hist_kernel<<<nblkc, 256, 0, stream>>>(dst, cnt, E, nbuck, nblkc);
    bucket_colscan_kernel<<<nbuck, 256, 0, stream>>>(cnt, total, nblkc);
    bucket_scan_kernel<<<1, 512, 0, stream>>>(total, bstart, nbuck, rowstart, N);
    partition_kernel<<<nblkc, 256, 0, stream>>>(src, dst, cnt, bstart, ebuf, E, nbuck, nblkc);
    build_csr_kernel<<<nbuck, 256, 0, stream>>>(ebuf, bstart, rowstart, dinv, csr_src, N);
    gemm1_mfma<<<gblocks, 256, 0, stream>>>(x, W1, dinv, h1s, N);
    gather1_kernel<<<gablocks, 256, 0, stream>>>(h1s, rowstart, csr_src, dinv, b1, agg1h, N);
    gemm2_mfma<<<gblocks, 256, 0, stream>>>(agg1h, W2, dinv, h2s, N);
    gather2_kernel<<<gablocks, 256, 0, stream>>>(h2s, rowstart, csr_src, dinv, b2, out, N);
}